// Round 17
// baseline (517.542 us; speedup 1.0000x reference)
//
#include <hip/hip_runtime.h>
#include <math.h>
#include <stdint.h>

// ---------------------------------------------------------------------------
// GroundingModule — round 17: hybrid A-format.
//   MODE 0 (v_p GEMM): A staged as SEPARATE Ah/Al bf16 units (r14's proven
//     conflict-free path, no unpack) + packed-u32 O store + stats epilogue.
//   MODE 1 (h GEMM):   A staged PACKED (vp_hl u32) with in-register unpack
//     (confined to the half-size GEMM) + affine epilogue (LN2 commutation).
// Everything else from r14-r16 kept: 2 blocks/CU, 256thr/4 waves, 128x192,
// single-phase k-loop, VMW(10), slot-XOR swizzles, branchless gelu,
// prep_A2 eliminated (stats in MODE0 epilogue + stats2 fold + colsums).
// ---------------------------------------------------------------------------

#define DEV __device__ __forceinline__

typedef __attribute__((ext_vector_type(8))) short short8v;   // 8 bf16
typedef __attribute__((ext_vector_type(4))) float f32x4;
typedef __attribute__((ext_vector_type(4))) uint32_t u32x4;

constexpr int KDIM  = 768;
constexpr int CHUNK = 32768;

// output offsets (floats) in return order
constexpr int OFF_KG   = 0;
constexpr int OFF_MI   = 65536;
constexpr int OFF_ST   = 69632;
constexpr int OFF_ET   = 71680;
constexpr int OFF_MASK = 73728;
constexpr int OFF_ORI  = 139264;

DEV float wave_sum(float v) { for (int o = 32; o; o >>= 1) v += __shfl_xor(v, o); return v; }
DEV float wave_max(float v) { for (int o = 32; o; o >>= 1) v = fmaxf(v, __shfl_xor(v, o)); return v; }

// branchless gelu: 0.5x(1+erf(x/sqrt2)), erf via A&S 7.1.26 (|err|<=1.5e-7)
DEV float gelu_fast(float x) {
    float z = x * 0.70710678118654752f;
    float s = fabsf(z);
    float t = __builtin_amdgcn_rcpf(fmaf(0.3275911f, s, 1.0f));
    float p = t * fmaf(t, fmaf(t, fmaf(t, fmaf(t, 1.061405429f, -1.453152027f),
                                       1.421413741f), -0.284496736f), 0.254829592f);
    float e = __expf(-s * s);
    float er = copysignf(1.0f - p * e, z);
    return 0.5f * x * (1.0f + er);
}

DEV short f2bf(float x) {                       // f32 -> bf16 (RNE)
    uint32_t u = __builtin_bit_cast(uint32_t, x);
    u = u + 0x7fffu + ((u >> 16) & 1u);
    return (short)(u >> 16);
}
DEV float bf2f(short b) {
    uint32_t u = ((uint32_t)(uint16_t)b) << 16;
    return __builtin_bit_cast(float, u);
}
DEV float asf(uint32_t u) { return __builtin_bit_cast(float, u); }

// pack f32 -> u32 (truncated-hi bits in TOP, RNE lo-bf16 of remainder in LOW)
DEV uint32_t packhl(float x) {
    uint32_t u  = __builtin_bit_cast(uint32_t, x);
    uint32_t hb = u & 0xffff0000u;
    float rem   = x - asf(hb);
    return hb | (uint32_t)(uint16_t)f2bf(rem);
}

DEV void gl_lds16(const void* g, void* l) {     // async 16B/lane global->LDS
    __builtin_amdgcn_global_load_lds(
        (const __attribute__((address_space(1))) uint32_t*)g,
        (__attribute__((address_space(3))) uint32_t*)l, 16, 0, 0);
}

// unpack 8 packed u32 -> hi short8v + lo short8v
DEV void unpack8(u32x4 p0, u32x4 p1, short8v& hi, short8v& lo) {
    u32x4 h, l;
    h.x = (p0.x >> 16) | (p0.y & 0xffff0000u);
    h.y = (p0.z >> 16) | (p0.w & 0xffff0000u);
    h.z = (p1.x >> 16) | (p1.y & 0xffff0000u);
    h.w = (p1.z >> 16) | (p1.w & 0xffff0000u);
    l.x = (p0.x & 0xffffu) | (p0.y << 16);
    l.y = (p0.z & 0xffffu) | (p0.w << 16);
    l.z = (p1.x & 0xffffu) | (p1.y << 16);
    l.w = (p1.z & 0xffffu) | (p1.w << 16);
    hi = __builtin_bit_cast(short8v, h);
    lo = __builtin_bit_cast(short8v, l);
}

// ---------------------------------------------------------------------------
// prep_A1: fused rowstats + LN-affine + hi/lo split (separate arrays).
__global__ __launch_bounds__(256)
void prep_A1(const float* __restrict__ X, const float* __restrict__ g,
             const float* __restrict__ b, short* __restrict__ Ah, short* __restrict__ Al)
{
    int w = threadIdx.x >> 6, lane = threadIdx.x & 63;
    int row = blockIdx.x * 4 + w;
    const float4* xr = (const float4*)(X + (size_t)row * KDIM);
    float4 xv[3]; float s = 0.f, ss = 0.f;
#pragma unroll
    for (int i = 0; i < 3; ++i) {
        xv[i] = xr[lane + i * 64];
        s  += xv[i].x + xv[i].y + xv[i].z + xv[i].w;
        ss += xv[i].x * xv[i].x + xv[i].y * xv[i].y + xv[i].z * xv[i].z + xv[i].w * xv[i].w;
    }
    s = wave_sum(s); ss = wave_sum(ss);
    float m = s * (1.f / 768.f), var = ss * (1.f / 768.f) - m * m;
    float sa = rsqrtf(var + 1e-5f), ta = -m * sa;
#pragma unroll
    for (int i = 0; i < 3; ++i) {
        int idx = lane + i * 64;
        float4 gv = ((const float4*)g)[idx];
        float4 bv = ((const float4*)b)[idx];
        float a0 = fmaf(fmaf(xv[i].x, sa, ta), gv.x, bv.x);
        float a1 = fmaf(fmaf(xv[i].y, sa, ta), gv.y, bv.y);
        float a2 = fmaf(fmaf(xv[i].z, sa, ta), gv.z, bv.z);
        float a3 = fmaf(fmaf(xv[i].w, sa, ta), gv.w, bv.w);
        short h0 = f2bf(a0), h1 = f2bf(a1), h2 = f2bf(a2), h3 = f2bf(a3);
        ushort4 hv, lv;
        hv.x = (uint16_t)h0; hv.y = (uint16_t)h1; hv.z = (uint16_t)h2; hv.w = (uint16_t)h3;
        lv.x = (uint16_t)f2bf(a0 - bf2f(h0)); lv.y = (uint16_t)f2bf(a1 - bf2f(h1));
        lv.z = (uint16_t)f2bf(a2 - bf2f(h2)); lv.w = (uint16_t)f2bf(a3 - bf2f(h3));
        ((ushort4*)(Ah + (size_t)row * KDIM))[idx] = hv;
        ((ushort4*)(Al + (size_t)row * KDIM))[idx] = lv;
    }
}

// ---------------------------------------------------------------------------
// prep_W: transpose + hi/lo split, optional per-k scale.
__global__ __launch_bounds__(256)
void prep_W(const float* __restrict__ W, const float* __restrict__ scale,
            short* __restrict__ Bh, short* __restrict__ Bl, int N)
{
    __shared__ float t[32][33];
    int bx = blockIdx.x, by = blockIdx.y;
    int lx = threadIdx.x & 31, ly = threadIdx.x >> 5;
#pragma unroll
    for (int r = 0; r < 32; r += 8)
        t[ly + r][lx] = W[(size_t)(by * 32 + ly + r) * N + bx * 32 + lx];
    __syncthreads();
    float sc = scale ? scale[by * 32 + lx] : 1.0f;
#pragma unroll
    for (int r = 0; r < 32; r += 8) {
        float v = t[lx][ly + r] * sc;              // k = by*32+lx
        short hi = f2bf(v);
        size_t o = (size_t)(bx * 32 + ly + r) * KDIM + by * 32 + lx;
        Bh[o] = hi;
        Bl[o] = f2bf(v - bf2f(hi));
    }
}

// ---------------------------------------------------------------------------
// colsums: c1[n] = sum_k g2[k]*W1[k][n];  c2[n] = b1[n] + sum_k lnb2[k]*W1[k][n]
__global__ __launch_bounds__(256)
void colsums(const float* __restrict__ W1, const float* __restrict__ g2,
             const float* __restrict__ lb2, const float* __restrict__ b1,
             float* __restrict__ c1, float* __restrict__ c2)
{
    int w = threadIdx.x >> 6, lane = threadIdx.x & 63;
    int n = blockIdx.x * 4 + w;                 // 0..383
    float s1 = 0.f, s2 = 0.f;
    for (int k = lane; k < 768; k += 64) {
        float wv = W1[(size_t)k * 384 + n];
        s1 += g2[k] * wv;
        s2 += lb2[k] * wv;
    }
    s1 = wave_sum(s1); s2 = wave_sum(s2);
    if (lane == 0) { c1[n] = s1; c2[n] = b1[n] + s2; }
}

// ---------------------------------------------------------------------------
// stats2: fold 8 column-partials per row -> (sa, ta) for the LN2+gate affine.
__global__ __launch_bounds__(256)
void stats2(const float* __restrict__ sums, float2* __restrict__ st2, int chunk_off)
{
    int r = chunk_off + blockIdx.x * 256 + threadIdx.x;
    float s = 0.f, ss = 0.f, d = 0.f;
#pragma unroll
    for (int p = 0; p < 8; ++p) {
        s  += sums[(size_t)(0 * 8 + p) * 65536 + r];
        ss += sums[(size_t)(1 * 8 + p) * 65536 + r];
        d  += sums[(size_t)(2 * 8 + p) * 65536 + r];
    }
    float gate = tanhf(d);
    float m = s * (1.f / 768.f), var = ss * (1.f / 768.f) - m * m;
    float den = rsqrtf(gate * gate * var + 1e-5f);
    st2[r] = make_float2(gate * den, -gate * m * den);
}

// ---------------------------------------------------------------------------
// Split-bf16 MFMA GEMM, hybrid A-format.  2 blocks/CU, 256 thr / 4 waves,
// BM=128 BN=192, BK=32, single-phase k-loop, 10 x 4KB units, VMW(10).
//   MODE 0: A = separate Ah/Al bf16 (64B rows); epilogue packed-u32 O + stats.
//   MODE 1: A = packed u32 (128B rows, reg unpack); epilogue affine + w2 dot.
#define VMW(N_) asm volatile("s_waitcnt vmcnt(" #N_ ")" ::: "memory")
#define SCB __builtin_amdgcn_sched_barrier(0)

#define STG(U_, KT_, KS_) gl_lds16(sp[U_] + (size_t)(KT_) * (KS_),            \
    lds + (((KT_) & 1) ? BUFSZ : 0) + (U_) * 4096 + toff)

#define STGALL(KT_) do {                                                      \
    STG(0, KT_, KSTA); STG(1, KT_, KSTA); STG(2, KT_, KSTA);                  \
    STG(3, KT_, KSTA); STG(4, KT_, 64); STG(5, KT_, 64); STG(6, KT_, 64);     \
    STG(7, KT_, 64); STG(8, KT_, 64); STG(9, KT_, 64); } while (0)

#define RDA(dst, BOFF) do { _Pragma("unroll")                                 \
    for (int mf = 0; mf < 4; ++mf) {                                          \
        int rA = wm * 64 + mf * 16 + lr;                                      \
        dst[mf] = *(const short8v*)(bb + (BOFF) + rA * 64 +                   \
                                    ((lh ^ ((rA >> 1) & 3)) << 4));           \
    } } while (0)

#define RDA2 do { RDA(ah, 0); RDA(al, 8192); } while (0)

#define RDAP do { _Pragma("unroll")                                           \
    for (int mf = 0; mf < 4; ++mf) {                                          \
        int rA = wm * 64 + mf * 16 + lr;                                      \
        const char* pr = bb + rA * 128;                                       \
        int x_ = rA & 7;                                                      \
        u32x4 p0 = *(const u32x4*)(pr + (((2 * lh) ^ x_) << 4));              \
        u32x4 p1 = *(const u32x4*)(pr + (((2 * lh + 1) ^ x_) << 4));          \
        unpack8(p0, p1, ah[mf], al[mf]);                                      \
    } } while (0)

#define RDB(dst, BOFF) do { _Pragma("unroll")                                 \
    for (int nf = 0; nf < 6; ++nf) {                                          \
        int rB = wn * 96 + nf * 16 + lr;                                      \
        dst[nf] = *(const short8v*)(bb + (BOFF) + rB * 64 +                   \
                                    ((lh ^ ((rB >> 1) & 3)) << 4));           \
    } } while (0)

#define BODY(KT_, NL_, ARD) do {                                              \
    if (NL_) { STGALL((KT_) + 1); }                                           \
    SCB;                                                                      \
    if (NL_) { VMW(10); } else { VMW(0); }                                    \
    SCB;                                                                      \
    __builtin_amdgcn_s_barrier();            /* buf[KT_] staged for all */    \
    const char* bb = lds + (((KT_) & 1) ? BUFSZ : 0);                         \
    ARD; RDB(bh, 16384); RDB(bl, 28672);                                      \
    asm volatile("s_waitcnt lgkmcnt(0)" ::: "memory");                        \
    SCB;                                                                      \
    __builtin_amdgcn_s_barrier();            /* reads done for all */         \
    __builtin_amdgcn_s_setprio(1);                                            \
    _Pragma("unroll")                                                         \
    for (int mf = 0; mf < 4; ++mf)                                            \
        _Pragma("unroll")                                                     \
        for (int nf = 0; nf < 6; ++nf) {                                      \
            acc[mf][nf] = __builtin_amdgcn_mfma_f32_16x16x32_bf16(            \
                ah[mf], bh[nf], acc[mf][nf], 0, 0, 0);                        \
            acc[mf][nf] = __builtin_amdgcn_mfma_f32_16x16x32_bf16(            \
                ah[mf], bl[nf], acc[mf][nf], 0, 0, 0);                        \
            acc[mf][nf] = __builtin_amdgcn_mfma_f32_16x16x32_bf16(            \
                al[mf], bh[nf], acc[mf][nf], 0, 0, 0);                        \
        }                                                                     \
    __builtin_amdgcn_s_setprio(0);                                            \
    SCB;                                                                      \
} while (0)

template<int MODE>
__global__ __launch_bounds__(256, 2)
void gemm8(const short* __restrict__ Ah_g, const short* __restrict__ Al_g,
           const uint32_t* __restrict__ Ap_g,
           const short* __restrict__ Bh_g, const short* __restrict__ Bl_g,
           const float* __restrict__ bias, uint32_t* __restrict__ O_hl,
           const float* __restrict__ qa_p, float* __restrict__ sums,
           const float2* __restrict__ st2, const float* __restrict__ c1,
           const float* __restrict__ c2, const float* __restrict__ w2,
           float* __restrict__ partials, int chunk_off)
{
    constexpr int BUFSZ = 40960;              // 40 KB per buffer
    constexpr int KSTA  = (MODE == 0) ? 64 : 128;   // A unit k-stride (bytes)
    extern __shared__ __align__(16) char lds[];

    const int t = threadIdx.x;
    const int w = t >> 6, lane = t & 63;
    const int lr = lane & 15, lh = lane >> 4;
    const int wm = w >> 1, wn = w & 1;        // 2 x 2 wave grid

    const int gx = gridDim.x, nwg = gx * gridDim.y;
    int bidx = blockIdx.y * gx + blockIdx.x;
    int wid = (bidx & 7) * (nwg >> 3) + (bidx >> 3);
    const int bx = wid % gx, by = wid / gx;
    const int row0 = by * 128, col0 = bx * 192;

    // stage source pointers (k=0)
    const int r_ = t >> 2, c_ = t & 3;
    const int swz_ = (c_ ^ ((r_ >> 1) & 3)) << 3;
    const int rA_ = t >> 3, cA_ = t & 7;
    const int toff = t * 16;
    const char* sp[10];
    if (MODE == 0) {
        sp[0] = (const char*)(Ah_g + (size_t)(row0 + r_)      * KDIM + swz_);
        sp[1] = (const char*)(Ah_g + (size_t)(row0 + 64 + r_) * KDIM + swz_);
        sp[2] = (const char*)(Al_g + (size_t)(row0 + r_)      * KDIM + swz_);
        sp[3] = (const char*)(Al_g + (size_t)(row0 + 64 + r_) * KDIM + swz_);
    } else {
#pragma unroll
        for (int u = 0; u < 4; ++u)
            sp[u] = (const char*)(Ap_g + (size_t)(row0 + u * 32 + rA_) * KDIM
                                       + ((cA_ ^ (rA_ & 7)) << 2));
    }
    sp[4] = (const char*)(Bh_g + (size_t)(col0 + r_)       * KDIM + swz_);
    sp[5] = (const char*)(Bh_g + (size_t)(col0 + 64 + r_)  * KDIM + swz_);
    sp[6] = (const char*)(Bh_g + (size_t)(col0 + 128 + r_) * KDIM + swz_);
    sp[7] = (const char*)(Bl_g + (size_t)(col0 + r_)       * KDIM + swz_);
    sp[8] = (const char*)(Bl_g + (size_t)(col0 + 64 + r_)  * KDIM + swz_);
    sp[9] = (const char*)(Bl_g + (size_t)(col0 + 128 + r_) * KDIM + swz_);

    f32x4 acc[4][6] = {};
    short8v ah[4], al[4], bh[6], bl[6];

    STGALL(0);
    SCB;

    if (MODE == 0) {
        for (int kt = 0; kt < 24; kt += 2) {
            BODY(kt,     true,           RDA2);
            BODY(kt + 1, (kt + 1 < 23),  RDA2);
        }
    } else {
        for (int kt = 0; kt < 24; kt += 2) {
            BODY(kt,     true,           RDAP);
            BODY(kt + 1, (kt + 1 < 23),  RDAP);
        }
    }

    if (MODE == 0) {
        // cache qa_p slice for this block: 4 batch rows x 192 cols.
        __syncthreads();
        float* qal = (float*)lds;
        int bbase = (chunk_off >> 5) + (row0 >> 5);
        for (int j = t; j < 768; j += 256)
            qal[j] = qa_p[(size_t)(bbase + j / 192) * 768 + col0 + (j % 192)];
        __syncthreads();
#pragma unroll
        for (int mf = 0; mf < 4; ++mf) {
            const int bp = wm * 2 + (mf >> 1);
#pragma unroll
            for (int q = 0; q < 4; ++q) {
                int m = row0 + wm * 64 + mf * 16 + lh * 4 + q;
                float s = 0.f, ssq = 0.f, d = 0.f;
#pragma unroll
                for (int nf = 0; nf < 6; ++nf) {
                    int ncol = wn * 96 + nf * 16 + lr;
                    int n = col0 + ncol;
                    float gv = gelu_fast(acc[mf][nf][q] + bias[n]);
                    O_hl[(size_t)m * 768 + n] = packhl(gv);
                    s += gv; ssq += gv * gv; d += gv * qal[bp * 192 + ncol];
                }
                for (int o = 1; o < 16; o <<= 1) {
                    s += __shfl_xor(s, o); ssq += __shfl_xor(ssq, o); d += __shfl_xor(d, o);
                }
                if (lr == 0) {
                    int gr = chunk_off + m;
                    int pc = bx * 2 + wn;
                    sums[(size_t)(0 * 8 + pc) * 65536 + gr] = s;
                    sums[(size_t)(1 * 8 + pc) * 65536 + gr] = ssq;
                    sums[(size_t)(2 * 8 + pc) * 65536 + gr] = d;
                }
            }
        }
    } else {
        float c1v[6], c2v[6], wv[6];
#pragma unroll
        for (int nf = 0; nf < 6; ++nf) {
            int n = col0 + wn * 96 + nf * 16 + lr;
            c1v[nf] = c1[n]; c2v[nf] = c2[n]; wv[nf] = w2[n];
        }
        float rs[4][4] = {};
#pragma unroll
        for (int mf = 0; mf < 4; ++mf)
#pragma unroll
            for (int q = 0; q < 4; ++q) {
                int gm = chunk_off + row0 + wm * 64 + mf * 16 + lh * 4 + q;
                float2 st = st2[gm];
#pragma unroll
                for (int nf = 0; nf < 6; ++nf) {
                    float h = fmaf(st.x, acc[mf][nf][q], fmaf(st.y, c1v[nf], c2v[nf]));
                    rs[mf][q] += gelu_fast(h) * wv[nf];
                }
            }
#pragma unroll
        for (int mf = 0; mf < 4; ++mf)
#pragma unroll
            for (int q = 0; q < 4; ++q) {
                float vv = rs[mf][q];
                vv += __shfl_xor(vv, 1); vv += __shfl_xor(vv, 2);
                vv += __shfl_xor(vv, 4); vv += __shfl_xor(vv, 8);
                if (lr == 0) {
                    int gm = chunk_off + row0 + wm * 64 + mf * 16 + lh * 4 + q;
                    partials[(size_t)(bx * 2 + wn) * 65536 + gm] = vv;
                }
            }
    }
}

// ---------------------------------------------------------------------------
// f32 fallback GEMM for the small qa projection.
constexpr int BKF = 16;
__global__ __launch_bounds__(256)
void rowstats(const float* __restrict__ X, float2* __restrict__ st, int M)
{
    int wave = threadIdx.x >> 6, lane = threadIdx.x & 63;
    int row = blockIdx.x * 4 + wave;
    if (row >= M) return;
    const float4* xr = reinterpret_cast<const float4*>(X + (size_t)row * KDIM);
    float s = 0.f, ss = 0.f;
#pragma unroll
    for (int i = 0; i < 3; ++i) {
        float4 v = xr[lane + i * 64];
        s  += v.x + v.y + v.z + v.w;
        ss += v.x * v.x + v.y * v.y + v.z * v.z + v.w * v.w;
    }
    s = wave_sum(s); ss = wave_sum(ss);
    if (lane == 0) {
        float m = s * (1.0f / 768.0f);
        float var = ss * (1.0f / 768.0f) - m * m;
        float rstd = rsqrtf(var + 1e-5f);
        st[row] = make_float2(rstd, -m * rstd);
    }
}

template<int BM, int BN, int TM, int TN>
__global__ __launch_bounds__(256)
void gemm_fused(const float* __restrict__ X, const float2* __restrict__ st,
                const float* __restrict__ gw, const float* __restrict__ gb,
                const float* __restrict__ W, const float* __restrict__ bias,
                float* __restrict__ out, int M, int N)
{
    static_assert((BM / TM) * (BN / TN) == 256, "256 threads");
    __shared__ float As[BKF][BM];
    __shared__ float Bs[BKF][BN];
    const int t = threadIdx.x;
    constexpr int TXN = BN / TN;
    const int tx = t % TXN;
    const int ty = t / TXN;
    const int row0 = blockIdx.y * BM;
    const int col0 = blockIdx.x * BN;
    float acc[TM][TN] = {};
    constexpr int A_IT = BM * BKF / 4 / 256;
    constexpr int B_IT = BKF * BN / 4 / 256;
    for (int k0 = 0; k0 < KDIM; k0 += BKF) {
#pragma unroll
        for (int i = 0; i < A_IT; ++i) {
            int idx = t + i * 256;
            int r = idx >> 2;
            int c = (idx & 3) << 2;
            float4 xv = *reinterpret_cast<const float4*>(X + (size_t)(row0 + r) * KDIM + k0 + c);
            float2 s = st[row0 + r];
            float4 gv = *reinterpret_cast<const float4*>(gw + k0 + c);
            float4 bv = *reinterpret_cast<const float4*>(gb + k0 + c);
            As[c + 0][r] = fmaf(fmaf(xv.x, s.x, s.y), gv.x, bv.x);
            As[c + 1][r] = fmaf(fmaf(xv.y, s.x, s.y), gv.y, bv.y);
            As[c + 2][r] = fmaf(fmaf(xv.z, s.x, s.y), gv.z, bv.z);
            As[c + 3][r] = fmaf(fmaf(xv.w, s.x, s.y), gv.w, bv.w);
        }
#pragma unroll
        for (int i = 0; i < B_IT; ++i) {
            int idx = t + i * 256;
            int r = idx / (BN / 4);
            int c = (idx % (BN / 4)) << 2;
            *reinterpret_cast<float4*>(&Bs[r][c]) =
                *reinterpret_cast<const float4*>(W + (size_t)(k0 + r) * N + col0 + c);
        }
        __syncthreads();
#pragma unroll
        for (int kk = 0; kk < BKF; ++kk) {
            float a[TM], b[TN];
#pragma unroll
            for (int i = 0; i < TM; i += 4)
                *reinterpret_cast<float4*>(&a[i]) = *reinterpret_cast<const float4*>(&As[kk][ty * TM + i]);
#pragma unroll
            for (int j = 0; j < TN; j += 4)
                *reinterpret_cast<float4*>(&b[j]) = *reinterpret_cast<const float4*>(&Bs[kk][tx * TN + j]);
#pragma unroll
            for (int i = 0; i < TM; ++i)
#pragma unroll
                for (int j = 0; j < TN; ++j)
                    acc[i][j] = fmaf(a[i], b[j], acc[i][j]);
        }
        __syncthreads();
    }
#pragma unroll
    for (int i = 0; i < TM; ++i) {
        size_t row = row0 + ty * TM + i;
#pragma unroll
        for (int j = 0; j < TN; j += 4) {
            int col = col0 + tx * TN + j;
            float4 o;
            o.x = gelu_fast(acc[i][j + 0] + bias[col + 0]);
            o.y = gelu_fast(acc[i][j + 1] + bias[col + 1]);
            o.z = gelu_fast(acc[i][j + 2] + bias[col + 2]);
            o.w = gelu_fast(acc[i][j + 3] + bias[col + 3]);
            *reinterpret_cast<float4*>(out + row * N + col) = o;
        }
    }
}

// ---------------------------------------------------------------------------
// head: logits = sum(4 partials)+b2 -> softmax -> smooth -> softmax -> decode.
__global__ __launch_bounds__(64)
void head_kernel(const float* __restrict__ partials, const float* __restrict__ b2,
                 const float* __restrict__ sigma_p, float* __restrict__ out)
{
    int b = blockIdx.x, lane = threadIdx.x;
    __shared__ float ok[36];
    __shared__ float kg[32];
    __shared__ int sel[2];

    if (lane < 36) ok[lane] = 0.f;
    __syncthreads();

    float x = -3.4e38f;
    if (lane < 32) {
        int row = b * 32 + lane;
        x = b2[0];
#pragma unroll
        for (int p = 0; p < 4; ++p) x += partials[(size_t)p * 65536 + row];
    }
    float mx = wave_max(x);
    float e = (lane < 32) ? expf(x - mx) : 0.f;
    float sum = wave_sum(e);
    float ori = e / sum;
    if (lane < 32) {
        out[OFF_ORI + b * 32 + lane] = ori;
        ok[lane + 2] = ori;
    }
    __syncthreads();

    float sg = sigma_p[0];
    float kern[5]; float ks = 0.f;
#pragma unroll
    for (int k = 0; k < 5; ++k) { float xx = (float)(k - 2) / sg; kern[k] = expf(-0.5f * xx * xx); ks += kern[k]; }
    float sm = -3.4e38f;
    if (lane < 32) {
        sm = 0.f;
#pragma unroll
        for (int k = 0; k < 5; ++k) sm += (kern[k] / ks) * ok[lane + k];
    }
    float mx2 = wave_max(sm);
    float e2 = (lane < 32) ? expf(sm - mx2) : 0.f;
    float sum2 = wave_sum(e2);
    float kgv = e2 / sum2;
    if (lane < 32) {
        out[OFF_KG + b * 32 + lane] = kgv;
        kg[lane] = kgv;
    }
    __syncthreads();

    if (lane == 0) {
        int pm = 0; float bv = kg[0];
        for (int i = 1; i < 32; ++i) if (kg[i] > bv) { bv = kg[i]; pm = i; }
        float cum[33]; cum[0] = 0.f;
        for (int i = 0; i < 32; ++i) cum[i + 1] = cum[i] + kg[i];
        float bs = -3.4e38f; int bst = 0, ben = 0;
        const int wsz[3] = {1, 3, 5};
        for (int wi = 0; wi < 3; ++wi) {
            int w = wsz[wi];
            for (int s = 0; s + w <= 32; ++s) {
                if (pm >= s && pm < s + w) {
                    float sc = cum[s + w] - cum[s];
                    if (sc > bs) { bs = sc; bst = s; ben = s + w; }
                }
            }
        }
        out[OFF_MI + b * 2 + 0] = (float)bst;
        out[OFF_MI + b * 2 + 1] = (float)ben;
        out[OFF_ST + b] = (float)bst / 31.0f;
        out[OFF_ET + b] = (float)ben / 31.0f;
        sel[0] = bst; sel[1] = ben;
    }
    __syncthreads();
    if (lane < 32)
        out[OFF_MASK + b * 32 + lane] = (lane >= sel[0] && lane <= sel[1]) ? 1.0f : 0.0f;
}

// ---------------------------------------------------------------------------
extern "C" void kernel_launch(void* const* d_in, const int* in_sizes, int n_in,
                              void* d_out, int out_size, void* d_ws, size_t ws_size,
                              hipStream_t stream)
{
    const float* v      = (const float*)d_in[0];
    const float* qa     = (const float*)d_in[1];
    const float* vp_lng = (const float*)d_in[2];
    const float* vp_lnb = (const float*)d_in[3];
    const float* vp_w   = (const float*)d_in[4];
    const float* vp_b   = (const float*)d_in[5];
    const float* qp_lng = (const float*)d_in[6];
    const float* qp_lnb = (const float*)d_in[7];
    const float* qp_w   = (const float*)d_in[8];
    const float* qp_b   = (const float*)d_in[9];
    const float* g_lng  = (const float*)d_in[10];
    const float* g_lnb  = (const float*)d_in[11];
    const float* g_w1   = (const float*)d_in[12];
    const float* g_b1   = (const float*)d_in[13];
    const float* g_w2   = (const float*)d_in[14];
    const float* g_b2   = (const float*)d_in[15];
    const float* sigma  = (const float*)d_in[16];
    float* outf = (float*)d_out;

    // workspace layout (~225 MB)
    short* A1h = (short*)d_ws;                           // CHUNK*768
    short* A1l = A1h + (size_t)CHUNK * KDIM;
    uint32_t* vp_hl = (uint32_t*)(A1l + (size_t)CHUNK * KDIM);   // CHUNK*768 u32
    short* B1h = (short*)(vp_hl + (size_t)CHUNK * KDIM); // 768*768
    short* B1l = B1h + 768 * KDIM;
    short* B2h = B1l + 768 * KDIM;                       // 384*768
    short* B2l = B2h + 384 * KDIM;
    float* qa_p = (float*)(B2l + 384 * KDIM);            // 2048*768
    float* st_qa = qa_p + 2048 * KDIM;                   // 2048*2
    float* partials = st_qa + 4096;                      // 4*65536
    float* sums = partials + 4 * 65536;                  // 3*8*65536
    float2* st2 = (float2*)(sums + 24 * 65536);          // 65536
    float* c1 = (float*)(st2 + 65536);                   // 384
    float* c2 = c1 + 384;                                // 384

    // qa path (small, f32 vector GEMM)
    rowstats<<<512, 256, 0, stream>>>(qa, (float2*)st_qa, 2048);
    gemm_fused<64, 64, 4, 4><<<dim3(12, 32), 256, 0, stream>>>(
        qa, (const float2*)st_qa, qp_lng, qp_lnb, qp_w, qp_b, qa_p, 2048, 768);

    // weight prep: B1 = split(vp_w); B2 = split(g_lng (.) g_w1); colsums c1/c2
    prep_W<<<dim3(24, 24), 256, 0, stream>>>(vp_w, nullptr, B1h, B1l, 768);
    prep_W<<<dim3(12, 24), 256, 0, stream>>>(g_w1, g_lng, B2h, B2l, 384);
    colsums<<<96, 256, 0, stream>>>(g_w1, g_lng, g_lnb, g_b1, c1, c2);

    constexpr int LDS8 = 81920;   // 2 bufs x 40 KB -> 2 blocks/CU

    for (int c = 0; c < 65536; c += CHUNK) {
        prep_A1<<<CHUNK / 4, 256, 0, stream>>>(v + (size_t)c * KDIM, vp_lng, vp_lnb, A1h, A1l);
        // v_p = gelu(A1 @ vp_w^T + vp_b) -> packed vp_hl + row stats partials
        gemm8<0><<<dim3(4, CHUNK / 128), 256, LDS8, stream>>>(
            A1h, A1l, nullptr, B1h, B1l, vp_b, vp_hl, qa_p, sums,
            nullptr, nullptr, nullptr, nullptr, nullptr, c);
        stats2<<<CHUNK / 256, 256, 0, stream>>>(sums, st2, c);
        // h = gelu(sa*(vp @ g2W1) + ta*c1 + c2); fused dot(g_w2) -> partials
        gemm8<1><<<dim3(2, CHUNK / 128), 256, LDS8, stream>>>(
            nullptr, nullptr, vp_hl, B2h, B2l, nullptr, nullptr, nullptr, nullptr,
            (const float2*)st2, c1, c2, g_w2, partials, c);
    }

    head_kernel<<<2048, 64, 0, stream>>>(partials, g_b2, sigma, outf);
}

// Round 18
// 496.481 us; speedup vs baseline: 1.0424x; 1.0424x over previous
//
#include <hip/hip_runtime.h>
#include <math.h>
#include <stdint.h>

// ---------------------------------------------------------------------------
// GroundingModule — round 18: r17 + cheap stats reduction in MODE0 epilogue.
//   Halving butterfly (add-before-select) reduces all 16 (mf,q)x{s,ssq,d}
//   triples in 90 shfls (was 192) and ends with lane lr holding entry lr ->
//   uniform 3-store per lane (was divergent lr==0 chains).  Div-free qa stage.
// Everything else identical to r17 (hybrid A-format, single-phase k-loop,
// VMW(10), 2 blocks/CU, LN2-affine commutation, branchless gelu).
// ---------------------------------------------------------------------------

#define DEV __device__ __forceinline__

typedef __attribute__((ext_vector_type(8))) short short8v;   // 8 bf16
typedef __attribute__((ext_vector_type(4))) float f32x4;
typedef __attribute__((ext_vector_type(4))) uint32_t u32x4;

constexpr int KDIM  = 768;
constexpr int CHUNK = 32768;

// output offsets (floats) in return order
constexpr int OFF_KG   = 0;
constexpr int OFF_MI   = 65536;
constexpr int OFF_ST   = 69632;
constexpr int OFF_ET   = 71680;
constexpr int OFF_MASK = 73728;
constexpr int OFF_ORI  = 139264;

DEV float wave_sum(float v) { for (int o = 32; o; o >>= 1) v += __shfl_xor(v, o); return v; }
DEV float wave_max(float v) { for (int o = 32; o; o >>= 1) v = fmaxf(v, __shfl_xor(v, o)); return v; }

// branchless gelu: 0.5x(1+erf(x/sqrt2)), erf via A&S 7.1.26 (|err|<=1.5e-7)
DEV float gelu_fast(float x) {
    float z = x * 0.70710678118654752f;
    float s = fabsf(z);
    float t = __builtin_amdgcn_rcpf(fmaf(0.3275911f, s, 1.0f));
    float p = t * fmaf(t, fmaf(t, fmaf(t, fmaf(t, 1.061405429f, -1.453152027f),
                                       1.421413741f), -0.284496736f), 0.254829592f);
    float e = __expf(-s * s);
    float er = copysignf(1.0f - p * e, z);
    return 0.5f * x * (1.0f + er);
}

DEV short f2bf(float x) {                       // f32 -> bf16 (RNE)
    uint32_t u = __builtin_bit_cast(uint32_t, x);
    u = u + 0x7fffu + ((u >> 16) & 1u);
    return (short)(u >> 16);
}
DEV float bf2f(short b) {
    uint32_t u = ((uint32_t)(uint16_t)b) << 16;
    return __builtin_bit_cast(float, u);
}
DEV float asf(uint32_t u) { return __builtin_bit_cast(float, u); }

// pack f32 -> u32 (truncated-hi bits in TOP, RNE lo-bf16 of remainder in LOW)
DEV uint32_t packhl(float x) {
    uint32_t u  = __builtin_bit_cast(uint32_t, x);
    uint32_t hb = u & 0xffff0000u;
    float rem   = x - asf(hb);
    return hb | (uint32_t)(uint16_t)f2bf(rem);
}

DEV void gl_lds16(const void* g, void* l) {     // async 16B/lane global->LDS
    __builtin_amdgcn_global_load_lds(
        (const __attribute__((address_space(1))) uint32_t*)g,
        (__attribute__((address_space(3))) uint32_t*)l, 16, 0, 0);
}

// unpack 8 packed u32 -> hi short8v + lo short8v
DEV void unpack8(u32x4 p0, u32x4 p1, short8v& hi, short8v& lo) {
    u32x4 h, l;
    h.x = (p0.x >> 16) | (p0.y & 0xffff0000u);
    h.y = (p0.z >> 16) | (p0.w & 0xffff0000u);
    h.z = (p1.x >> 16) | (p1.y & 0xffff0000u);
    h.w = (p1.z >> 16) | (p1.w & 0xffff0000u);
    l.x = (p0.x & 0xffffu) | (p0.y << 16);
    l.y = (p0.z & 0xffffu) | (p0.w << 16);
    l.z = (p1.x & 0xffffu) | (p1.y << 16);
    l.w = (p1.z & 0xffffu) | (p1.w << 16);
    hi = __builtin_bit_cast(short8v, h);
    lo = __builtin_bit_cast(short8v, l);
}

// ---------------------------------------------------------------------------
// prep_A1: fused rowstats + LN-affine + hi/lo split (separate arrays).
__global__ __launch_bounds__(256)
void prep_A1(const float* __restrict__ X, const float* __restrict__ g,
             const float* __restrict__ b, short* __restrict__ Ah, short* __restrict__ Al)
{
    int w = threadIdx.x >> 6, lane = threadIdx.x & 63;
    int row = blockIdx.x * 4 + w;
    const float4* xr = (const float4*)(X + (size_t)row * KDIM);
    float4 xv[3]; float s = 0.f, ss = 0.f;
#pragma unroll
    for (int i = 0; i < 3; ++i) {
        xv[i] = xr[lane + i * 64];
        s  += xv[i].x + xv[i].y + xv[i].z + xv[i].w;
        ss += xv[i].x * xv[i].x + xv[i].y * xv[i].y + xv[i].z * xv[i].z + xv[i].w * xv[i].w;
    }
    s = wave_sum(s); ss = wave_sum(ss);
    float m = s * (1.f / 768.f), var = ss * (1.f / 768.f) - m * m;
    float sa = rsqrtf(var + 1e-5f), ta = -m * sa;
#pragma unroll
    for (int i = 0; i < 3; ++i) {
        int idx = lane + i * 64;
        float4 gv = ((const float4*)g)[idx];
        float4 bv = ((const float4*)b)[idx];
        float a0 = fmaf(fmaf(xv[i].x, sa, ta), gv.x, bv.x);
        float a1 = fmaf(fmaf(xv[i].y, sa, ta), gv.y, bv.y);
        float a2 = fmaf(fmaf(xv[i].z, sa, ta), gv.z, bv.z);
        float a3 = fmaf(fmaf(xv[i].w, sa, ta), gv.w, bv.w);
        short h0 = f2bf(a0), h1 = f2bf(a1), h2 = f2bf(a2), h3 = f2bf(a3);
        ushort4 hv, lv;
        hv.x = (uint16_t)h0; hv.y = (uint16_t)h1; hv.z = (uint16_t)h2; hv.w = (uint16_t)h3;
        lv.x = (uint16_t)f2bf(a0 - bf2f(h0)); lv.y = (uint16_t)f2bf(a1 - bf2f(h1));
        lv.z = (uint16_t)f2bf(a2 - bf2f(h2)); lv.w = (uint16_t)f2bf(a3 - bf2f(h3));
        ((ushort4*)(Ah + (size_t)row * KDIM))[idx] = hv;
        ((ushort4*)(Al + (size_t)row * KDIM))[idx] = lv;
    }
}

// ---------------------------------------------------------------------------
// prep_W: transpose + hi/lo split, optional per-k scale.
__global__ __launch_bounds__(256)
void prep_W(const float* __restrict__ W, const float* __restrict__ scale,
            short* __restrict__ Bh, short* __restrict__ Bl, int N)
{
    __shared__ float t[32][33];
    int bx = blockIdx.x, by = blockIdx.y;
    int lx = threadIdx.x & 31, ly = threadIdx.x >> 5;
#pragma unroll
    for (int r = 0; r < 32; r += 8)
        t[ly + r][lx] = W[(size_t)(by * 32 + ly + r) * N + bx * 32 + lx];
    __syncthreads();
    float sc = scale ? scale[by * 32 + lx] : 1.0f;
#pragma unroll
    for (int r = 0; r < 32; r += 8) {
        float v = t[lx][ly + r] * sc;              // k = by*32+lx
        short hi = f2bf(v);
        size_t o = (size_t)(bx * 32 + ly + r) * KDIM + by * 32 + lx;
        Bh[o] = hi;
        Bl[o] = f2bf(v - bf2f(hi));
    }
}

// ---------------------------------------------------------------------------
// colsums: c1[n] = sum_k g2[k]*W1[k][n];  c2[n] = b1[n] + sum_k lnb2[k]*W1[k][n]
__global__ __launch_bounds__(256)
void colsums(const float* __restrict__ W1, const float* __restrict__ g2,
             const float* __restrict__ lb2, const float* __restrict__ b1,
             float* __restrict__ c1, float* __restrict__ c2)
{
    int w = threadIdx.x >> 6, lane = threadIdx.x & 63;
    int n = blockIdx.x * 4 + w;                 // 0..383
    float s1 = 0.f, s2 = 0.f;
    for (int k = lane; k < 768; k += 64) {
        float wv = W1[(size_t)k * 384 + n];
        s1 += g2[k] * wv;
        s2 += lb2[k] * wv;
    }
    s1 = wave_sum(s1); s2 = wave_sum(s2);
    if (lane == 0) { c1[n] = s1; c2[n] = b1[n] + s2; }
}

// ---------------------------------------------------------------------------
// stats2: fold 8 column-partials per row -> (sa, ta) for the LN2+gate affine.
__global__ __launch_bounds__(256)
void stats2(const float* __restrict__ sums, float2* __restrict__ st2, int chunk_off)
{
    int r = chunk_off + blockIdx.x * 256 + threadIdx.x;
    float s = 0.f, ss = 0.f, d = 0.f;
#pragma unroll
    for (int p = 0; p < 8; ++p) {
        s  += sums[(size_t)(0 * 8 + p) * 65536 + r];
        ss += sums[(size_t)(1 * 8 + p) * 65536 + r];
        d  += sums[(size_t)(2 * 8 + p) * 65536 + r];
    }
    float gate = tanhf(d);
    float m = s * (1.f / 768.f), var = ss * (1.f / 768.f) - m * m;
    float den = rsqrtf(gate * gate * var + 1e-5f);
    st2[r] = make_float2(gate * den, -gate * m * den);
}

// ---------------------------------------------------------------------------
// Split-bf16 MFMA GEMM, hybrid A-format.  2 blocks/CU, 256 thr / 4 waves,
// BM=128 BN=192, BK=32, single-phase k-loop, 10 x 4KB units, VMW(10).
#define VMW(N_) asm volatile("s_waitcnt vmcnt(" #N_ ")" ::: "memory")
#define SCB __builtin_amdgcn_sched_barrier(0)

#define STG(U_, KT_, KS_) gl_lds16(sp[U_] + (size_t)(KT_) * (KS_),            \
    lds + (((KT_) & 1) ? BUFSZ : 0) + (U_) * 4096 + toff)

#define STGALL(KT_) do {                                                      \
    STG(0, KT_, KSTA); STG(1, KT_, KSTA); STG(2, KT_, KSTA);                  \
    STG(3, KT_, KSTA); STG(4, KT_, 64); STG(5, KT_, 64); STG(6, KT_, 64);     \
    STG(7, KT_, 64); STG(8, KT_, 64); STG(9, KT_, 64); } while (0)

#define RDA(dst, BOFF) do { _Pragma("unroll")                                 \
    for (int mf = 0; mf < 4; ++mf) {                                          \
        int rA = wm * 64 + mf * 16 + lr;                                      \
        dst[mf] = *(const short8v*)(bb + (BOFF) + rA * 64 +                   \
                                    ((lh ^ ((rA >> 1) & 3)) << 4));           \
    } } while (0)

#define RDA2 do { RDA(ah, 0); RDA(al, 8192); } while (0)

#define RDAP do { _Pragma("unroll")                                           \
    for (int mf = 0; mf < 4; ++mf) {                                          \
        int rA = wm * 64 + mf * 16 + lr;                                      \
        const char* pr = bb + rA * 128;                                       \
        int x_ = rA & 7;                                                      \
        u32x4 p0 = *(const u32x4*)(pr + (((2 * lh) ^ x_) << 4));              \
        u32x4 p1 = *(const u32x4*)(pr + (((2 * lh + 1) ^ x_) << 4));          \
        unpack8(p0, p1, ah[mf], al[mf]);                                      \
    } } while (0)

#define RDB(dst, BOFF) do { _Pragma("unroll")                                 \
    for (int nf = 0; nf < 6; ++nf) {                                          \
        int rB = wn * 96 + nf * 16 + lr;                                      \
        dst[nf] = *(const short8v*)(bb + (BOFF) + rB * 64 +                   \
                                    ((lh ^ ((rB >> 1) & 3)) << 4));           \
    } } while (0)

#define BODY(KT_, NL_, ARD) do {                                              \
    if (NL_) { STGALL((KT_) + 1); }                                           \
    SCB;                                                                      \
    if (NL_) { VMW(10); } else { VMW(0); }                                    \
    SCB;                                                                      \
    __builtin_amdgcn_s_barrier();            /* buf[KT_] staged for all */    \
    const char* bb = lds + (((KT_) & 1) ? BUFSZ : 0);                         \
    ARD; RDB(bh, 16384); RDB(bl, 28672);                                      \
    asm volatile("s_waitcnt lgkmcnt(0)" ::: "memory");                        \
    SCB;                                                                      \
    __builtin_amdgcn_s_barrier();            /* reads done for all */         \
    __builtin_amdgcn_s_setprio(1);                                            \
    _Pragma("unroll")                                                         \
    for (int mf = 0; mf < 4; ++mf)                                            \
        _Pragma("unroll")                                                     \
        for (int nf = 0; nf < 6; ++nf) {                                      \
            acc[mf][nf] = __builtin_amdgcn_mfma_f32_16x16x32_bf16(            \
                ah[mf], bh[nf], acc[mf][nf], 0, 0, 0);                        \
            acc[mf][nf] = __builtin_amdgcn_mfma_f32_16x16x32_bf16(            \
                ah[mf], bl[nf], acc[mf][nf], 0, 0, 0);                        \
            acc[mf][nf] = __builtin_amdgcn_mfma_f32_16x16x32_bf16(            \
                al[mf], bh[nf], acc[mf][nf], 0, 0, 0);                        \
        }                                                                     \
    __builtin_amdgcn_s_setprio(0);                                            \
    SCB;                                                                      \
} while (0)

template<int MODE>
__global__ __launch_bounds__(256, 2)
void gemm8(const short* __restrict__ Ah_g, const short* __restrict__ Al_g,
           const uint32_t* __restrict__ Ap_g,
           const short* __restrict__ Bh_g, const short* __restrict__ Bl_g,
           const float* __restrict__ bias, uint32_t* __restrict__ O_hl,
           const float* __restrict__ qa_p, float* __restrict__ sums,
           const float2* __restrict__ st2, const float* __restrict__ c1,
           const float* __restrict__ c2, const float* __restrict__ w2,
           float* __restrict__ partials, int chunk_off)
{
    constexpr int BUFSZ = 40960;              // 40 KB per buffer
    constexpr int KSTA  = (MODE == 0) ? 64 : 128;   // A unit k-stride (bytes)
    extern __shared__ __align__(16) char lds[];

    const int t = threadIdx.x;
    const int w = t >> 6, lane = t & 63;
    const int lr = lane & 15, lh = lane >> 4;
    const int wm = w >> 1, wn = w & 1;        // 2 x 2 wave grid

    const int gx = gridDim.x, nwg = gx * gridDim.y;
    int bidx = blockIdx.y * gx + blockIdx.x;
    int wid = (bidx & 7) * (nwg >> 3) + (bidx >> 3);
    const int bx = wid % gx, by = wid / gx;
    const int row0 = by * 128, col0 = bx * 192;

    // stage source pointers (k=0)
    const int r_ = t >> 2, c_ = t & 3;
    const int swz_ = (c_ ^ ((r_ >> 1) & 3)) << 3;
    const int rA_ = t >> 3, cA_ = t & 7;
    const int toff = t * 16;
    const char* sp[10];
    if (MODE == 0) {
        sp[0] = (const char*)(Ah_g + (size_t)(row0 + r_)      * KDIM + swz_);
        sp[1] = (const char*)(Ah_g + (size_t)(row0 + 64 + r_) * KDIM + swz_);
        sp[2] = (const char*)(Al_g + (size_t)(row0 + r_)      * KDIM + swz_);
        sp[3] = (const char*)(Al_g + (size_t)(row0 + 64 + r_) * KDIM + swz_);
    } else {
#pragma unroll
        for (int u = 0; u < 4; ++u)
            sp[u] = (const char*)(Ap_g + (size_t)(row0 + u * 32 + rA_) * KDIM
                                       + ((cA_ ^ (rA_ & 7)) << 2));
    }
    sp[4] = (const char*)(Bh_g + (size_t)(col0 + r_)       * KDIM + swz_);
    sp[5] = (const char*)(Bh_g + (size_t)(col0 + 64 + r_)  * KDIM + swz_);
    sp[6] = (const char*)(Bh_g + (size_t)(col0 + 128 + r_) * KDIM + swz_);
    sp[7] = (const char*)(Bl_g + (size_t)(col0 + r_)       * KDIM + swz_);
    sp[8] = (const char*)(Bl_g + (size_t)(col0 + 64 + r_)  * KDIM + swz_);
    sp[9] = (const char*)(Bl_g + (size_t)(col0 + 128 + r_) * KDIM + swz_);

    f32x4 acc[4][6] = {};
    short8v ah[4], al[4], bh[6], bl[6];

    STGALL(0);
    SCB;

    if (MODE == 0) {
        for (int kt = 0; kt < 24; kt += 2) {
            BODY(kt,     true,           RDA2);
            BODY(kt + 1, (kt + 1 < 23),  RDA2);
        }
    } else {
        for (int kt = 0; kt < 24; kt += 2) {
            BODY(kt,     true,           RDAP);
            BODY(kt + 1, (kt + 1 < 23),  RDAP);
        }
    }

    if (MODE == 0) {
        // cache qa_p slice for this block: 4 batch rows x 192 cols (div-free).
        __syncthreads();
        float* qal = (float*)lds;
#pragma unroll
        for (int rr = 0; rr < 4; ++rr) {
            int bbase = (chunk_off >> 5) + (row0 >> 5);
            if (t < 192)
                qal[rr * 192 + t] = qa_p[(size_t)(bbase + rr) * 768 + col0 + t];
        }
        __syncthreads();

        // per-(mf,q) partials: s, ssq, d (accumulate over own 6 columns)
        float p[16][3];
#pragma unroll
        for (int mf = 0; mf < 4; ++mf) {
            const int bp = wm * 2 + (mf >> 1);
#pragma unroll
            for (int q = 0; q < 4; ++q) {
                int m = row0 + wm * 64 + mf * 16 + lh * 4 + q;
                float s = 0.f, ssq = 0.f, d = 0.f;
#pragma unroll
                for (int nf = 0; nf < 6; ++nf) {
                    int ncol = wn * 96 + nf * 16 + lr;
                    int n = col0 + ncol;
                    float gv = gelu_fast(acc[mf][nf][q] + bias[n]);
                    O_hl[(size_t)m * 768 + n] = packhl(gv);
                    s += gv; ssq += gv * gv; d += gv * qal[bp * 192 + ncol];
                }
                p[mf * 4 + q][0] = s; p[mf * 4 + q][1] = ssq; p[mf * 4 + q][2] = d;
            }
        }

        // halving butterfly over lr (16 lanes): entry idx bit_k chosen by lr
        // bit_k at step mask 2^k; final lane lr holds totals for idx == lr.
        float r8[8][3], r4[4][3], r2[2][3], r1[3];
#pragma unroll
        for (int j = 0; j < 8; ++j)
#pragma unroll
            for (int v = 0; v < 3; ++v) {
                float e = p[2 * j][v]     + __shfl_xor(p[2 * j][v], 1);
                float o = p[2 * j + 1][v] + __shfl_xor(p[2 * j + 1][v], 1);
                r8[j][v] = (lr & 1) ? o : e;
            }
#pragma unroll
        for (int j = 0; j < 4; ++j)
#pragma unroll
            for (int v = 0; v < 3; ++v) {
                float e = r8[2 * j][v]     + __shfl_xor(r8[2 * j][v], 2);
                float o = r8[2 * j + 1][v] + __shfl_xor(r8[2 * j + 1][v], 2);
                r4[j][v] = (lr & 2) ? o : e;
            }
#pragma unroll
        for (int j = 0; j < 2; ++j)
#pragma unroll
            for (int v = 0; v < 3; ++v) {
                float e = r4[2 * j][v]     + __shfl_xor(r4[2 * j][v], 4);
                float o = r4[2 * j + 1][v] + __shfl_xor(r4[2 * j + 1][v], 4);
                r2[j][v] = (lr & 4) ? o : e;
            }
#pragma unroll
        for (int v = 0; v < 3; ++v) {
            float e = r2[0][v] + __shfl_xor(r2[0][v], 8);
            float o = r2[1][v] + __shfl_xor(r2[1][v], 8);
            r1[v] = (lr & 8) ? o : e;
        }

        // lane lr holds idx=lr -> mf = lr>>2, q = lr&3; uniform stores.
        {
            int gr = chunk_off + row0 + wm * 64 + (lr >> 2) * 16 + lh * 4 + (lr & 3);
            int pc = bx * 2 + wn;
            sums[(size_t)(0 * 8 + pc) * 65536 + gr] = r1[0];
            sums[(size_t)(1 * 8 + pc) * 65536 + gr] = r1[1];
            sums[(size_t)(2 * 8 + pc) * 65536 + gr] = r1[2];
        }
    } else {
        float c1v[6], c2v[6], wv[6];
#pragma unroll
        for (int nf = 0; nf < 6; ++nf) {
            int n = col0 + wn * 96 + nf * 16 + lr;
            c1v[nf] = c1[n]; c2v[nf] = c2[n]; wv[nf] = w2[n];
        }
        float rs[4][4] = {};
#pragma unroll
        for (int mf = 0; mf < 4; ++mf)
#pragma unroll
            for (int q = 0; q < 4; ++q) {
                int gm = chunk_off + row0 + wm * 64 + mf * 16 + lh * 4 + q;
                float2 st = st2[gm];
#pragma unroll
                for (int nf = 0; nf < 6; ++nf) {
                    float h = fmaf(st.x, acc[mf][nf][q], fmaf(st.y, c1v[nf], c2v[nf]));
                    rs[mf][q] += gelu_fast(h) * wv[nf];
                }
            }
#pragma unroll
        for (int mf = 0; mf < 4; ++mf)
#pragma unroll
            for (int q = 0; q < 4; ++q) {
                float vv = rs[mf][q];
                vv += __shfl_xor(vv, 1); vv += __shfl_xor(vv, 2);
                vv += __shfl_xor(vv, 4); vv += __shfl_xor(vv, 8);
                if (lr == 0) {
                    int gm = chunk_off + row0 + wm * 64 + mf * 16 + lh * 4 + q;
                    partials[(size_t)(bx * 2 + wn) * 65536 + gm] = vv;
                }
            }
    }
}

// ---------------------------------------------------------------------------
// f32 fallback GEMM for the small qa projection.
constexpr int BKF = 16;
__global__ __launch_bounds__(256)
void rowstats(const float* __restrict__ X, float2* __restrict__ st, int M)
{
    int wave = threadIdx.x >> 6, lane = threadIdx.x & 63;
    int row = blockIdx.x * 4 + wave;
    if (row >= M) return;
    const float4* xr = reinterpret_cast<const float4*>(X + (size_t)row * KDIM);
    float s = 0.f, ss = 0.f;
#pragma unroll
    for (int i = 0; i < 3; ++i) {
        float4 v = xr[lane + i * 64];
        s  += v.x + v.y + v.z + v.w;
        ss += v.x * v.x + v.y * v.y + v.z * v.z + v.w * v.w;
    }
    s = wave_sum(s); ss = wave_sum(ss);
    if (lane == 0) {
        float m = s * (1.0f / 768.0f);
        float var = ss * (1.0f / 768.0f) - m * m;
        float rstd = rsqrtf(var + 1e-5f);
        st[row] = make_float2(rstd, -m * rstd);
    }
}

template<int BM, int BN, int TM, int TN>
__global__ __launch_bounds__(256)
void gemm_fused(const float* __restrict__ X, const float2* __restrict__ st,
                const float* __restrict__ gw, const float* __restrict__ gb,
                const float* __restrict__ W, const float* __restrict__ bias,
                float* __restrict__ out, int M, int N)
{
    static_assert((BM / TM) * (BN / TN) == 256, "256 threads");
    __shared__ float As[BKF][BM];
    __shared__ float Bs[BKF][BN];
    const int t = threadIdx.x;
    constexpr int TXN = BN / TN;
    const int tx = t % TXN;
    const int ty = t / TXN;
    const int row0 = blockIdx.y * BM;
    const int col0 = blockIdx.x * BN;
    float acc[TM][TN] = {};
    constexpr int A_IT = BM * BKF / 4 / 256;
    constexpr int B_IT = BKF * BN / 4 / 256;
    for (int k0 = 0; k0 < KDIM; k0 += BKF) {
#pragma unroll
        for (int i = 0; i < A_IT; ++i) {
            int idx = t + i * 256;
            int r = idx >> 2;
            int c = (idx & 3) << 2;
            float4 xv = *reinterpret_cast<const float4*>(X + (size_t)(row0 + r) * KDIM + k0 + c);
            float2 s = st[row0 + r];
            float4 gv = *reinterpret_cast<const float4*>(gw + k0 + c);
            float4 bv = *reinterpret_cast<const float4*>(gb + k0 + c);
            As[c + 0][r] = fmaf(fmaf(xv.x, s.x, s.y), gv.x, bv.x);
            As[c + 1][r] = fmaf(fmaf(xv.y, s.x, s.y), gv.y, bv.y);
            As[c + 2][r] = fmaf(fmaf(xv.z, s.x, s.y), gv.z, bv.z);
            As[c + 3][r] = fmaf(fmaf(xv.w, s.x, s.y), gv.w, bv.w);
        }
#pragma unroll
        for (int i = 0; i < B_IT; ++i) {
            int idx = t + i * 256;
            int r = idx / (BN / 4);
            int c = (idx % (BN / 4)) << 2;
            *reinterpret_cast<float4*>(&Bs[r][c]) =
                *reinterpret_cast<const float4*>(W + (size_t)(k0 + r) * N + col0 + c);
        }
        __syncthreads();
#pragma unroll
        for (int kk = 0; kk < BKF; ++kk) {
            float a[TM], b[TN];
#pragma unroll
            for (int i = 0; i < TM; i += 4)
                *reinterpret_cast<float4*>(&a[i]) = *reinterpret_cast<const float4*>(&As[kk][ty * TM + i]);
#pragma unroll
            for (int j = 0; j < TN; j += 4)
                *reinterpret_cast<float4*>(&b[j]) = *reinterpret_cast<const float4*>(&Bs[kk][tx * TN + j]);
#pragma unroll
            for (int i = 0; i < TM; ++i)
#pragma unroll
                for (int j = 0; j < TN; ++j)
                    acc[i][j] = fmaf(a[i], b[j], acc[i][j]);
        }
        __syncthreads();
    }
#pragma unroll
    for (int i = 0; i < TM; ++i) {
        size_t row = row0 + ty * TM + i;
#pragma unroll
        for (int j = 0; j < TN; j += 4) {
            int col = col0 + tx * TN + j;
            float4 o;
            o.x = gelu_fast(acc[i][j + 0] + bias[col + 0]);
            o.y = gelu_fast(acc[i][j + 1] + bias[col + 1]);
            o.z = gelu_fast(acc[i][j + 2] + bias[col + 2]);
            o.w = gelu_fast(acc[i][j + 3] + bias[col + 3]);
            *reinterpret_cast<float4*>(out + row * N + col) = o;
        }
    }
}

// ---------------------------------------------------------------------------
// head: logits = sum(4 partials)+b2 -> softmax -> smooth -> softmax -> decode.
__global__ __launch_bounds__(64)
void head_kernel(const float* __restrict__ partials, const float* __restrict__ b2,
                 const float* __restrict__ sigma_p, float* __restrict__ out)
{
    int b = blockIdx.x, lane = threadIdx.x;
    __shared__ float ok[36];
    __shared__ float kg[32];
    __shared__ int sel[2];

    if (lane < 36) ok[lane] = 0.f;
    __syncthreads();

    float x = -3.4e38f;
    if (lane < 32) {
        int row = b * 32 + lane;
        x = b2[0];
#pragma unroll
        for (int p = 0; p < 4; ++p) x += partials[(size_t)p * 65536 + row];
    }
    float mx = wave_max(x);
    float e = (lane < 32) ? expf(x - mx) : 0.f;
    float sum = wave_sum(e);
    float ori = e / sum;
    if (lane < 32) {
        out[OFF_ORI + b * 32 + lane] = ori;
        ok[lane + 2] = ori;
    }
    __syncthreads();

    float sg = sigma_p[0];
    float kern[5]; float ks = 0.f;
#pragma unroll
    for (int k = 0; k < 5; ++k) { float xx = (float)(k - 2) / sg; kern[k] = expf(-0.5f * xx * xx); ks += kern[k]; }
    float sm = -3.4e38f;
    if (lane < 32) {
        sm = 0.f;
#pragma unroll
        for (int k = 0; k < 5; ++k) sm += (kern[k] / ks) * ok[lane + k];
    }
    float mx2 = wave_max(sm);
    float e2 = (lane < 32) ? expf(sm - mx2) : 0.f;
    float sum2 = wave_sum(e2);
    float kgv = e2 / sum2;
    if (lane < 32) {
        out[OFF_KG + b * 32 + lane] = kgv;
        kg[lane] = kgv;
    }
    __syncthreads();

    if (lane == 0) {
        int pm = 0; float bv = kg[0];
        for (int i = 1; i < 32; ++i) if (kg[i] > bv) { bv = kg[i]; pm = i; }
        float cum[33]; cum[0] = 0.f;
        for (int i = 0; i < 32; ++i) cum[i + 1] = cum[i] + kg[i];
        float bs = -3.4e38f; int bst = 0, ben = 0;
        const int wsz[3] = {1, 3, 5};
        for (int wi = 0; wi < 3; ++wi) {
            int w = wsz[wi];
            for (int s = 0; s + w <= 32; ++s) {
                if (pm >= s && pm < s + w) {
                    float sc = cum[s + w] - cum[s];
                    if (sc > bs) { bs = sc; bst = s; ben = s + w; }
                }
            }
        }
        out[OFF_MI + b * 2 + 0] = (float)bst;
        out[OFF_MI + b * 2 + 1] = (float)ben;
        out[OFF_ST + b] = (float)bst / 31.0f;
        out[OFF_ET + b] = (float)ben / 31.0f;
        sel[0] = bst; sel[1] = ben;
    }
    __syncthreads();
    if (lane < 32)
        out[OFF_MASK + b * 32 + lane] = (lane >= sel[0] && lane <= sel[1]) ? 1.0f : 0.0f;
}

// ---------------------------------------------------------------------------
extern "C" void kernel_launch(void* const* d_in, const int* in_sizes, int n_in,
                              void* d_out, int out_size, void* d_ws, size_t ws_size,
                              hipStream_t stream)
{
    const float* v      = (const float*)d_in[0];
    const float* qa     = (const float*)d_in[1];
    const float* vp_lng = (const float*)d_in[2];
    const float* vp_lnb = (const float*)d_in[3];
    const float* vp_w   = (const float*)d_in[4];
    const float* vp_b   = (const float*)d_in[5];
    const float* qp_lng = (const float*)d_in[6];
    const float* qp_lnb = (const float*)d_in[7];
    const float* qp_w   = (const float*)d_in[8];
    const float* qp_b   = (const float*)d_in[9];
    const float* g_lng  = (const float*)d_in[10];
    const float* g_lnb  = (const float*)d_in[11];
    const float* g_w1   = (const float*)d_in[12];
    const float* g_b1   = (const float*)d_in[13];
    const float* g_w2   = (const float*)d_in[14];
    const float* g_b2   = (const float*)d_in[15];
    const float* sigma  = (const float*)d_in[16];
    float* outf = (float*)d_out;

    // workspace layout (~225 MB)
    short* A1h = (short*)d_ws;                           // CHUNK*768
    short* A1l = A1h + (size_t)CHUNK * KDIM;
    uint32_t* vp_hl = (uint32_t*)(A1l + (size_t)CHUNK * KDIM);   // CHUNK*768 u32
    short* B1h = (short*)(vp_hl + (size_t)CHUNK * KDIM); // 768*768
    short* B1l = B1h + 768 * KDIM;
    short* B2h = B1l + 768 * KDIM;                       // 384*768
    short* B2l = B2h + 384 * KDIM;
    float* qa_p = (float*)(B2l + 384 * KDIM);            // 2048*768
    float* st_qa = qa_p + 2048 * KDIM;                   // 2048*2
    float* partials = st_qa + 4096;                      // 4*65536
    float* sums = partials + 4 * 65536;                  // 3*8*65536
    float2* st2 = (float2*)(sums + 24 * 65536);          // 65536
    float* c1 = (float*)(st2 + 65536);                   // 384
    float* c2 = c1 + 384;                                // 384

    // qa path (small, f32 vector GEMM)
    rowstats<<<512, 256, 0, stream>>>(qa, (float2*)st_qa, 2048);
    gemm_fused<64, 64, 4, 4><<<dim3(12, 32), 256, 0, stream>>>(
        qa, (const float2*)st_qa, qp_lng, qp_lnb, qp_w, qp_b, qa_p, 2048, 768);

    // weight prep: B1 = split(vp_w); B2 = split(g_lng (.) g_w1); colsums c1/c2
    prep_W<<<dim3(24, 24), 256, 0, stream>>>(vp_w, nullptr, B1h, B1l, 768);
    prep_W<<<dim3(12, 24), 256, 0, stream>>>(g_w1, g_lng, B2h, B2l, 384);
    colsums<<<96, 256, 0, stream>>>(g_w1, g_lng, g_lnb, g_b1, c1, c2);

    constexpr int LDS8 = 81920;   // 2 bufs x 40 KB -> 2 blocks/CU

    for (int c = 0; c < 65536; c += CHUNK) {
        prep_A1<<<CHUNK / 4, 256, 0, stream>>>(v + (size_t)c * KDIM, vp_lng, vp_lnb, A1h, A1l);
        // v_p = gelu(A1 @ vp_w^T + vp_b) -> packed vp_hl + row stats partials
        gemm8<0><<<dim3(4, CHUNK / 128), 256, LDS8, stream>>>(
            A1h, A1l, nullptr, B1h, B1l, vp_b, vp_hl, qa_p, sums,
            nullptr, nullptr, nullptr, nullptr, nullptr, c);
        stats2<<<CHUNK / 256, 256, 0, stream>>>(sums, st2, c);
        // h = gelu(sa*(vp @ g2W1) + ta*c1 + c2); fused dot(g_w2) -> partials
        gemm8<1><<<dim3(2, CHUNK / 128), 256, LDS8, stream>>>(
            nullptr, nullptr, vp_hl, B2h, B2l, nullptr, nullptr, nullptr, nullptr,
            (const float2*)st2, c1, c2, g_w2, partials, c);
    }

    head_kernel<<<2048, 64, 0, stream>>>(partials, g_b2, sigma, outf);
}